// Round 3
// baseline (143.431 us; speedup 1.0000x reference)
//
#include <hip/hip_runtime.h>

// MMD loss: source(4096x256 f32), target(4096x256 f32) -> scalar f32.
// 3 dispatches:
//   prep        : bf16 cast of concat, fp32 row norms sq[8192],
//                 per-block column partial sums (no atomics)
//   finalize_bw : reduce column partials -> ||s||^2, S1=sum(sq) -> store
//                 c = log2e * inv_bandwidth / 16 ; zero tile counter
//   mmd_tiles   : triangular 128x128 tiles of T*T^T, BK=64 as two 32-slabs
//                 (global_load_lds w=16, conflict-free 64B-row ds_read_b128),
//                 mfma 16x16x32 bf16, 1-exp2 epilogue (e,e^2,e^4,e^8,e^16),
//                 fence+ticket last-block final reduction -> d_out
#define N_TOT 8192
#define NB    4096
#define DDIM  256
#define NTILE 64
#define NBLK  (NTILE * (NTILE + 1) / 2)   // 2080
#define PREP_BLKS 256
#define ROWS_PB   (N_TOT / PREP_BLKS)     // 32 rows/block, 8 per wave

typedef __bf16 bf16x8 __attribute__((ext_vector_type(8)));
typedef float  f32x4  __attribute__((ext_vector_type(4)));

__device__ inline unsigned short f2bf_rne(float x) {
    unsigned int u = __float_as_uint(x);
    unsigned int r = (u + 0x7fffu + ((u >> 16) & 1u)) >> 16;
    return (unsigned short)r;
}

__device__ inline void gl2lds16(const unsigned short* g, unsigned short* l) {
    __builtin_amdgcn_global_load_lds(
        (const __attribute__((address_space(1))) unsigned int*)g,
        (__attribute__((address_space(3))) unsigned int*)l, 16, 0, 0);
}

// ws layout (floats): [2]=c=log2e*inv_bw/16, [3]=counter(u32),
// [512..8703]=sq[8192], [16384..18463]=part[2080],
// [32768..98303]=colp[256*256]; byte 524288..: bf16 total (4 MB)

__global__ __launch_bounds__(256) void prep(const float* __restrict__ src,
                                            const float* __restrict__ tgt,
                                            float* __restrict__ sq,
                                            unsigned short* __restrict__ totb,
                                            float* __restrict__ colp) {
    __shared__ float cs[4 * 256];
    int t = threadIdx.x, w = t >> 6, lane = t & 63;
    int row0 = blockIdx.x * ROWS_PB + w * (ROWS_PB / 4);
    float4 csum = {0.f, 0.f, 0.f, 0.f};
    #pragma unroll
    for (int r = 0; r < ROWS_PB / 4; ++r) {
        int row = row0 + r;
        const float* rp = (row < NB) ? (src + (size_t)row * DDIM)
                                     : (tgt + (size_t)(row - NB) * DDIM);
        float4 v = ((const float4*)rp)[lane];
        ushort4 o;
        o.x = f2bf_rne(v.x); o.y = f2bf_rne(v.y);
        o.z = f2bf_rne(v.z); o.w = f2bf_rne(v.w);
        ((ushort4*)(totb + (size_t)row * DDIM))[lane] = o;
        float s = v.x*v.x + v.y*v.y + v.z*v.z + v.w*v.w;
        #pragma unroll
        for (int off = 32; off > 0; off >>= 1) s += __shfl_down(s, off);
        if (lane == 0) sq[row] = s;
        csum.x += v.x; csum.y += v.y; csum.z += v.z; csum.w += v.w;
    }
    cs[w * 256 + lane * 4 + 0] = csum.x;
    cs[w * 256 + lane * 4 + 1] = csum.y;
    cs[w * 256 + lane * 4 + 2] = csum.z;
    cs[w * 256 + lane * 4 + 3] = csum.w;
    __syncthreads();
    colp[blockIdx.x * 256 + t] = cs[t] + cs[256 + t] + cs[512 + t] + cs[768 + t];
}

__global__ void finalize_bw(const float* __restrict__ colp,
                            const float* __restrict__ sq,
                            float* __restrict__ wsf) {
    __shared__ float redA[4], redB[4];
    int t = threadIdx.x, lane = t & 63, w = t >> 6;
    float sv0 = 0.f, sv1 = 0.f, sv2 = 0.f, sv3 = 0.f;
    for (int b = 0; b < PREP_BLKS; b += 4) {
        sv0 += colp[(b + 0) * 256 + t];
        sv1 += colp[(b + 1) * 256 + t];
        sv2 += colp[(b + 2) * 256 + t];
        sv3 += colp[(b + 3) * 256 + t];
    }
    float sv = (sv0 + sv1) + (sv2 + sv3);
    float s1 = 0.f;
    for (int i = t; i < N_TOT; i += 256) s1 += sq[i];
    float v2 = sv * sv;
    #pragma unroll
    for (int off = 32; off > 0; off >>= 1) {
        s1 += __shfl_down(s1, off);
        v2 += __shfl_down(v2, off);
    }
    if (lane == 0) { redA[w] = s1; redB[w] = v2; }
    __syncthreads();
    if (t == 0) {
        float S1   = redA[0] + redA[1] + redA[2] + redA[3];
        float sdot = redB[0] + redB[1] + redB[2] + redB[3];
        float bw_sum = 2.0f * (float)N_TOT * S1 - 2.0f * sdot;
        double denom = (double)N_TOT * (double)N_TOT - (double)N_TOT;
        float bandwidth = (float)((double)bw_sum / denom) * 0.25f;
        wsf[2] = (1.0f / bandwidth) * 0.0625f * 1.44269504f;  // c
        ((unsigned int*)wsf)[3] = 0u;                          // tile counter
    }
}

__global__ __launch_bounds__(256) void mmd_tiles(const unsigned short* __restrict__ totb,
                                                 const float* __restrict__ sq,
                                                 float* __restrict__ wsf,
                                                 float* __restrict__ part,
                                                 float* __restrict__ out) {
    __shared__ unsigned short lds_a[8192];   // 2 slabs x [128 rows][32 k]
    __shared__ unsigned short lds_b[8192];
    __shared__ float redf[4];
    __shared__ int amlast;

    // decode upper-triangular (ti, tj) from 1-D block index
    int idx = blockIdx.x;
    int ti = (int)((129.0f - sqrtf(16641.0f - 8.0f * (float)idx)) * 0.5f);
    if (ti > 63) ti = 63;
    if (ti < 0)  ti = 0;
    while ((ti * (129 - ti)) / 2 > idx) --ti;
    while (((ti + 1) * (128 - ti)) / 2 <= idx) ++ti;
    int tj = ti + idx - (ti * (129 - ti)) / 2;

    int t = threadIdx.x;
    int wid = t >> 6, lane = t & 63;
    int rl = lane & 15, q = lane >> 4;
    int gi0 = ti * 128, gj0 = tj * 128;
    int ia = (wid >> 1) * 64, jb = (wid & 1) * 64;

    // staging decode: instr i owns chunk c = i*256 + t  (1024 x 16B per matrix)
    const unsigned short* gA[4]; const unsigned short* gB[4];
    unsigned short* lA[4]; unsigned short* lB[4];
    #pragma unroll
    for (int i = 0; i < 4; ++i) {
        int c = i * 256 + t;
        int slab = c >> 9, rem = c & 511;
        int row = rem >> 2, kg = rem & 3;
        int col = slab * 32 + kg * 8;
        gA[i] = totb + (size_t)(gi0 + row) * DDIM + col;
        gB[i] = totb + (size_t)(gj0 + row) * DDIM + col;
        lA[i] = &lds_a[c * 8];
        lB[i] = &lds_b[c * 8];
    }

    f32x4 acc[4][4];
    #pragma unroll
    for (int m = 0; m < 4; ++m)
        #pragma unroll
        for (int n = 0; n < 4; ++n) acc[m][n] = (f32x4){0.f, 0.f, 0.f, 0.f};

    for (int k0 = 0; k0 < DDIM; k0 += 64) {
        #pragma unroll
        for (int i = 0; i < 4; ++i) {
            gl2lds16(gA[i] + k0, lA[i]);
            gl2lds16(gB[i] + k0, lB[i]);
        }
        __syncthreads();
        #pragma unroll
        for (int h = 0; h < 2; ++h) {
            bf16x8 av[4], bv[4];
            #pragma unroll
            for (int m = 0; m < 4; ++m)
                av[m] = *(const bf16x8*)&lds_a[h * 4096 + (ia + m * 16 + rl) * 32 + q * 8];
            #pragma unroll
            for (int n = 0; n < 4; ++n)
                bv[n] = *(const bf16x8*)&lds_b[h * 4096 + (jb + n * 16 + rl) * 32 + q * 8];
            #pragma unroll
            for (int m = 0; m < 4; ++m)
                #pragma unroll
                for (int n = 0; n < 4; ++n)
                    acc[m][n] = __builtin_amdgcn_mfma_f32_16x16x32_bf16(av[m], bv[n], acc[m][n], 0, 0, 0);
        }
        __syncthreads();
    }

    // epilogue: x = (2*acc - sqi - sqj)*c ; e1 = 2^x ; sum e1+e1^2+e1^4+e1^8+e1^16
    float c  = wsf[2];
    float tc = 2.0f * c;
    float local = 0.f;
    #pragma unroll
    for (int m = 0; m < 4; ++m) {
        f32x4 sqi = *(const f32x4*)(sq + gi0 + ia + m * 16 + q * 4);
        f32x4 ai;
        ai[0] = sqi[0] * c; ai[1] = sqi[1] * c; ai[2] = sqi[2] * c; ai[3] = sqi[3] * c;
        #pragma unroll
        for (int n = 0; n < 4; ++n) {
            float bj = sq[gj0 + jb + n * 16 + rl] * c;
            #pragma unroll
            for (int e = 0; e < 4; ++e) {
                float x  = __builtin_fmaf(acc[m][n][e], tc, -(ai[e] + bj));
                float e1 = __builtin_amdgcn_exp2f(x);
                float e2 = e1 * e1, e4 = e2 * e2, e8 = e4 * e4;
                local += ((e1 + e2) + (e4 + e8)) + e8 * e8;
            }
        }
    }
    #pragma unroll
    for (int off = 32; off > 0; off >>= 1) local += __shfl_down(local, off);
    if (lane == 0) redf[wid] = local;
    __syncthreads();
    if (t == 0) {
        float tot = redf[0] + redf[1] + redf[2] + redf[3];
        float scale = (((ti < 32) == (tj < 32)) ? 1.0f : -1.0f) * ((ti == tj) ? 1.0f : 2.0f);
        part[idx] = tot * scale;
        __threadfence();
        unsigned int old = atomicAdd((unsigned int*)&wsf[3], 1u);
        amlast = (old == NBLK - 1) ? 1 : 0;
    }
    __syncthreads();
    if (amlast) {
        __threadfence();
        float s = 0.f;
        for (int i = t; i < NBLK; i += 256) s += part[i];
        #pragma unroll
        for (int off = 32; off > 0; off >>= 1) s += __shfl_down(s, off);
        if (lane == 0) redf[wid] = s;
        __syncthreads();
        if (t == 0)
            out[0] = (redf[0] + redf[1] + redf[2] + redf[3]) * (1.0f / ((float)NB * (float)NB));
    }
}

extern "C" void kernel_launch(void* const* d_in, const int* in_sizes, int n_in,
                              void* d_out, int out_size, void* d_ws, size_t ws_size,
                              hipStream_t stream) {
    const float* src = (const float*)d_in[0];
    const float* tgt = (const float*)d_in[1];
    float* wsf  = (float*)d_ws;
    float* sq   = wsf + 512;
    float* part = wsf + 16384;
    float* colp = wsf + 32768;
    unsigned short* totb = (unsigned short*)((char*)d_ws + 524288);

    prep<<<PREP_BLKS, 256, 0, stream>>>(src, tgt, sq, totb, colp);
    finalize_bw<<<1, 256, 0, stream>>>(colp, sq, wsf);
    mmd_tiles<<<NBLK, 256, 0, stream>>>(totb, sq, wsf, part, (float*)d_out);
}

// Round 4
// 135.622 us; speedup vs baseline: 1.0576x; 1.0576x over previous
//
#include <hip/hip_runtime.h>

// MMD loss: source(4096x256 f32), target(4096x256 f32) -> scalar f32.
// 3 dispatches:
//   prep        : bf16 cast of concat, fp32 row norms sq[8192],
//                 per-block column partials colp[128][256] (no atomics)
//   finalize_bw : reduce colp -> ||s||^2, S1=sum(sq) -> c = log2e*inv_bw/16,
//                 zero tile ticket counter
//   mmd_tiles   : triangular 128x128 tiles of T*T^T, BK=32 double-buffered
//                 (DMA k+1 issued BEFORE compute k -> latency hidden),
//                 swizzled LDS (2-way banks = free), mfma 16x16x32 bf16,
//                 1-exp2 epilogue, fence+ticket last-block reduce -> d_out
#define N_TOT 8192
#define NB    4096
#define DDIM  256
#define NTILE 64
#define NBLK  (NTILE * (NTILE + 1) / 2)   // 2080
#define PREP_BLKS 128
#define ROWS_PB   (N_TOT / PREP_BLKS)     // 64 rows/block, 16 per wave

typedef __bf16 bf16x8 __attribute__((ext_vector_type(8)));
typedef float  f32x4  __attribute__((ext_vector_type(4)));

__device__ inline unsigned short f2bf_rne(float x) {
    unsigned int u = __float_as_uint(x);
    unsigned int r = (u + 0x7fffu + ((u >> 16) & 1u)) >> 16;
    return (unsigned short)r;
}

__device__ inline void gl2lds16(const unsigned short* g, unsigned short* l) {
    __builtin_amdgcn_global_load_lds(
        (const __attribute__((address_space(1))) unsigned int*)g,
        (__attribute__((address_space(3))) unsigned int*)l, 16, 0, 0);
}

// ws layout (floats): [2]=c, [3]=ticket(u32), [512..8703]=sq[8192],
// [16384..18463]=part[2080], [32768..65535]=colp[128*256];
// byte 524288..: bf16 total (4 MB)

__global__ __launch_bounds__(256) void prep(const float* __restrict__ src,
                                            const float* __restrict__ tgt,
                                            float* __restrict__ sq,
                                            unsigned short* __restrict__ totb,
                                            float* __restrict__ colp) {
    __shared__ float cs[4 * 256];
    int t = threadIdx.x, w = t >> 6, lane = t & 63;
    int row0 = blockIdx.x * ROWS_PB + w * (ROWS_PB / 4);
    float4 csum = {0.f, 0.f, 0.f, 0.f};
    #pragma unroll
    for (int r = 0; r < ROWS_PB / 4; ++r) {
        int row = row0 + r;
        const float* rp = (row < NB) ? (src + (size_t)row * DDIM)
                                     : (tgt + (size_t)(row - NB) * DDIM);
        float4 v = ((const float4*)rp)[lane];
        ushort4 o;
        o.x = f2bf_rne(v.x); o.y = f2bf_rne(v.y);
        o.z = f2bf_rne(v.z); o.w = f2bf_rne(v.w);
        ((ushort4*)(totb + (size_t)row * DDIM))[lane] = o;
        float s = v.x*v.x + v.y*v.y + v.z*v.z + v.w*v.w;
        #pragma unroll
        for (int off = 32; off > 0; off >>= 1) s += __shfl_down(s, off);
        if (lane == 0) sq[row] = s;
        csum.x += v.x; csum.y += v.y; csum.z += v.z; csum.w += v.w;
    }
    cs[w * 256 + lane * 4 + 0] = csum.x;
    cs[w * 256 + lane * 4 + 1] = csum.y;
    cs[w * 256 + lane * 4 + 2] = csum.z;
    cs[w * 256 + lane * 4 + 3] = csum.w;
    __syncthreads();
    colp[blockIdx.x * 256 + t] = (cs[t] + cs[256 + t]) + (cs[512 + t] + cs[768 + t]);
}

__global__ void finalize_bw(const float* __restrict__ colp,
                            const float* __restrict__ sq,
                            float* __restrict__ wsf) {
    __shared__ float redA[4], redB[4];
    int t = threadIdx.x, lane = t & 63, w = t >> 6;
    float a[8];
    #pragma unroll
    for (int u = 0; u < 8; ++u) a[u] = 0.f;
    for (int b = 0; b < PREP_BLKS; b += 8) {
        #pragma unroll
        for (int u = 0; u < 8; ++u) a[u] += colp[(b + u) * 256 + t];
    }
    float sv = ((a[0] + a[1]) + (a[2] + a[3])) + ((a[4] + a[5]) + (a[6] + a[7]));
    float s[8];
    #pragma unroll
    for (int u = 0; u < 8; ++u) s[u] = 0.f;
    for (int i = 0; i < 32; i += 8) {
        #pragma unroll
        for (int u = 0; u < 8; ++u) s[u] += sq[(i + u) * 256 + t];
    }
    float s1 = ((s[0] + s[1]) + (s[2] + s[3])) + ((s[4] + s[5]) + (s[6] + s[7]));
    float v2 = sv * sv;
    #pragma unroll
    for (int off = 32; off > 0; off >>= 1) {
        s1 += __shfl_down(s1, off);
        v2 += __shfl_down(v2, off);
    }
    if (lane == 0) { redA[w] = s1; redB[w] = v2; }
    __syncthreads();
    if (t == 0) {
        float S1   = redA[0] + redA[1] + redA[2] + redA[3];
        float sdot = redB[0] + redB[1] + redB[2] + redB[3];
        float bw_sum = 2.0f * (float)N_TOT * S1 - 2.0f * sdot;
        double denom = (double)N_TOT * (double)N_TOT - (double)N_TOT;
        float bandwidth = (float)((double)bw_sum / denom) * 0.25f;
        wsf[2] = (1.0f / bandwidth) * 0.0625f * 1.44269504f;  // c = log2e/(16*bw)
        ((unsigned int*)wsf)[3] = 0u;                          // tile ticket
    }
}

__global__ __launch_bounds__(256) void mmd_tiles(const unsigned short* __restrict__ totb,
                                                 const float* __restrict__ sq,
                                                 float* __restrict__ wsf,
                                                 float* __restrict__ part,
                                                 float* __restrict__ out) {
    __shared__ unsigned short lds_a[2][4096];  // [buf][128 rows x 32 k], swizzled
    __shared__ unsigned short lds_b[2][4096];
    __shared__ float redf[4];
    __shared__ int amlast;

    // decode upper-triangular (ti, tj) from 1-D block index
    int idx = blockIdx.x;
    int ti = (int)((129.0f - sqrtf(16641.0f - 8.0f * (float)idx)) * 0.5f);
    if (ti > 63) ti = 63;
    if (ti < 0)  ti = 0;
    while ((ti * (129 - ti)) / 2 > idx) --ti;
    while (((ti + 1) * (128 - ti)) / 2 <= idx) ++ti;
    int tj = ti + idx - (ti * (129 - ti)) / 2;

    int t = threadIdx.x;
    int wid = t >> 6, lane = t & 63;
    int rl = lane & 15, q = lane >> 4;
    int gi0 = ti * 128, gj0 = tj * 128;
    int ia = (wid >> 1) * 64, jb = (wid & 1) * 64;

    float c = wsf[2];   // issue early; used only in epilogue

    // Staging: chunk c0=t, c1=t+256; row=c>>2, pos p=c&3 holds global granule
    // g=(p-(row>>1))&3  (swizzle). LDS addr = c*16B (wave-contiguous for DMA).
    int r0 = t >> 2, p0 = t & 3;
    int g0 = (p0 - (r0 >> 1)) & 3;
    int r1 = r0 + 64;
    int g1 = (p0 - (r1 >> 1)) & 3;
    const unsigned short* gA0 = totb + (size_t)(gi0 + r0) * DDIM + g0 * 8;
    const unsigned short* gA1 = totb + (size_t)(gi0 + r1) * DDIM + g1 * 8;
    const unsigned short* gB0 = totb + (size_t)(gj0 + r0) * DDIM + g0 * 8;
    const unsigned short* gB1 = totb + (size_t)(gj0 + r1) * DDIM + g1 * 8;

    // Read offsets (shorts): row R, k-granule q lives at pos (q+(R>>1))&3
    int offA[4], offB[4];
    #pragma unroll
    for (int m = 0; m < 4; ++m) {
        int R = ia + m * 16 + rl;
        offA[m] = R * 32 + ((q + (R >> 1)) & 3) * 8;
    }
    #pragma unroll
    for (int n = 0; n < 4; ++n) {
        int R = jb + n * 16 + rl;
        offB[n] = R * 32 + ((q + (R >> 1)) & 3) * 8;
    }

    f32x4 acc[4][4];
    #pragma unroll
    for (int m = 0; m < 4; ++m)
        #pragma unroll
        for (int n = 0; n < 4; ++n) acc[m][n] = (f32x4){0.f, 0.f, 0.f, 0.f};

    // prologue DMA for k=0 into buf0
    gl2lds16(gA0, &lds_a[0][t * 8]);
    gl2lds16(gA1, &lds_a[0][(t + 256) * 8]);
    gl2lds16(gB0, &lds_b[0][t * 8]);
    gl2lds16(gB1, &lds_b[0][(t + 256) * 8]);
    __syncthreads();

    #pragma unroll
    for (int k = 0; k < 8; ++k) {
        const int cur = k & 1;
        if (k < 7) {                     // prefetch k+1 into the other buffer
            const int nk0 = (k + 1) * 32;
            const int nb  = cur ^ 1;
            gl2lds16(gA0 + nk0, &lds_a[nb][t * 8]);
            gl2lds16(gA1 + nk0, &lds_a[nb][(t + 256) * 8]);
            gl2lds16(gB0 + nk0, &lds_b[nb][t * 8]);
            gl2lds16(gB1 + nk0, &lds_b[nb][(t + 256) * 8]);
        }
        bf16x8 av[4], bv[4];
        #pragma unroll
        for (int m = 0; m < 4; ++m) av[m] = *(const bf16x8*)&lds_a[cur][offA[m]];
        #pragma unroll
        for (int n = 0; n < 4; ++n) bv[n] = *(const bf16x8*)&lds_b[cur][offB[n]];
        #pragma unroll
        for (int m = 0; m < 4; ++m)
            #pragma unroll
            for (int n = 0; n < 4; ++n)
                acc[m][n] = __builtin_amdgcn_mfma_f32_16x16x32_bf16(av[m], bv[n], acc[m][n], 0, 0, 0);
        __syncthreads();   // drains prefetch DMA + protects buffer reuse
    }

    // epilogue: x = (2*acc - sqi - sqj)*c ; e1=2^x ; sum e1+e1^2+e1^4+e1^8+e1^16
    float tc = 2.0f * c;
    float local = 0.f;
    #pragma unroll
    for (int m = 0; m < 4; ++m) {
        f32x4 sqi = *(const f32x4*)(sq + gi0 + ia + m * 16 + q * 4);
        f32x4 ai;
        ai[0] = sqi[0] * c; ai[1] = sqi[1] * c; ai[2] = sqi[2] * c; ai[3] = sqi[3] * c;
        #pragma unroll
        for (int n = 0; n < 4; ++n) {
            float bj = sq[gj0 + jb + n * 16 + rl] * c;
            #pragma unroll
            for (int e = 0; e < 4; ++e) {
                float x  = __builtin_fmaf(acc[m][n][e], tc, -(ai[e] + bj));
                float e1 = __builtin_amdgcn_exp2f(x);
                float e2 = e1 * e1, e4 = e2 * e2, e8 = e4 * e4;
                local += ((e1 + e2) + (e4 + e8)) + e8 * e8;
            }
        }
    }
    #pragma unroll
    for (int off = 32; off > 0; off >>= 1) local += __shfl_down(local, off);
    if (lane == 0) redf[wid] = local;
    __syncthreads();
    if (t == 0) {
        float tot = redf[0] + redf[1] + redf[2] + redf[3];
        float scale = (((ti < 32) == (tj < 32)) ? 1.0f : -1.0f) * ((ti == tj) ? 1.0f : 2.0f);
        part[idx] = tot * scale;
        __threadfence();
        unsigned int old = atomicAdd((unsigned int*)&wsf[3], 1u);
        amlast = (old == NBLK - 1) ? 1 : 0;
    }
    __syncthreads();
    if (amlast) {
        __threadfence();
        float a[8];
        #pragma unroll
        for (int u = 0; u < 8; ++u) a[u] = 0.f;
        #pragma unroll
        for (int u = 0; u < 8; ++u) a[u] = part[u * 256 + t];
        float s = ((a[0] + a[1]) + (a[2] + a[3])) + ((a[4] + a[5]) + (a[6] + a[7]));
        if (t < NBLK - 2048) s += part[2048 + t];
        #pragma unroll
        for (int off = 32; off > 0; off >>= 1) s += __shfl_down(s, off);
        if (lane == 0) redf[wid] = s;
        __syncthreads();
        if (t == 0)
            out[0] = (redf[0] + redf[1] + redf[2] + redf[3]) * (1.0f / ((float)NB * (float)NB));
    }
}

extern "C" void kernel_launch(void* const* d_in, const int* in_sizes, int n_in,
                              void* d_out, int out_size, void* d_ws, size_t ws_size,
                              hipStream_t stream) {
    const float* src = (const float*)d_in[0];
    const float* tgt = (const float*)d_in[1];
    float* wsf  = (float*)d_ws;
    float* sq   = wsf + 512;
    float* part = wsf + 16384;
    float* colp = wsf + 32768;
    unsigned short* totb = (unsigned short*)((char*)d_ws + 524288);

    prep<<<PREP_BLKS, 256, 0, stream>>>(src, tgt, sq, totb, colp);
    finalize_bw<<<1, 256, 0, stream>>>(colp, sq, wsf);
    mmd_tiles<<<NBLK, 256, 0, stream>>>(totb, sq, wsf, part, (float*)d_out);
}